// Round 1
// baseline (209.489 us; speedup 1.0000x reference)
//
#include <hip/hip_runtime.h>

#define N_ 8192
#define INF_ 512
#define OUTF_ 256
#define KVSPLIT 4
#define BK 64
#define TILES_PER_SPLIT (N_ / KVSPLIT / BK)   // 32

typedef float f32x4 __attribute__((ext_vector_type(4)));
typedef __bf16 bf16x8 __attribute__((ext_vector_type(8)));

__device__ __forceinline__ unsigned short f2bf(float f) {
  union { float f; unsigned u; } v; v.f = f;
  unsigned r = v.u + 0x7fffu + ((v.u >> 16) & 1u);
  return (unsigned short)(r >> 16);
}

// ---------------------------------------------------------------------------
// Kernel 1: h = x @ W (f32 accum). Emits h (bf16), h*a (bf16), h^T (bf16).
// ---------------------------------------------------------------------------
__global__ __launch_bounds__(256) void k_gemm_h(
    const float* __restrict__ x, const float* __restrict__ W,
    const float* __restrict__ a,
    unsigned short* __restrict__ hK, unsigned short* __restrict__ hQ,
    unsigned short* __restrict__ hT)
{
  __shared__ float xT[32][68];
  __shared__ float Wt[32][68];
  int tid = threadIdx.x;
  int tc = tid & 15, tr = tid >> 4;
  int r0 = blockIdx.x * 64;
  int c0 = blockIdx.y * 64;
  float acc[4][4] = {};
#pragma unroll 1
  for (int kt = 0; kt < 16; ++kt) {
    int k0 = kt * 32;
    __syncthreads();
    {
      int row = tid >> 2;
      int kc = (tid & 3) * 8;
      const float* src = x + (size_t)(r0 + row) * INF_ + k0 + kc;
      float4 v0 = *(const float4*)src;
      float4 v1 = *(const float4*)(src + 4);
      xT[kc+0][row] = v0.x; xT[kc+1][row] = v0.y;
      xT[kc+2][row] = v0.z; xT[kc+3][row] = v0.w;
      xT[kc+4][row] = v1.x; xT[kc+5][row] = v1.y;
      xT[kc+6][row] = v1.z; xT[kc+7][row] = v1.w;
    }
    {
      int kr = tid >> 3;
      int cc = (tid & 7) * 8;
      const float* src = W + (size_t)(k0 + kr) * OUTF_ + c0 + cc;
      float4 v0 = *(const float4*)src;
      float4 v1 = *(const float4*)(src + 4);
      *(float4*)&Wt[kr][cc]   = v0;
      *(float4*)&Wt[kr][cc+4] = v1;
    }
    __syncthreads();
#pragma unroll
    for (int k = 0; k < 32; ++k) {
      float av[4], bv[4];
      *(float4*)av = *(const float4*)&xT[k][tr*4];
      *(float4*)bv = *(const float4*)&Wt[k][tc*4];
#pragma unroll
      for (int i = 0; i < 4; ++i)
#pragma unroll
        for (int j = 0; j < 4; ++j)
          acc[i][j] = fmaf(av[i], bv[j], acc[i][j]);
    }
  }
  float av[4];
#pragma unroll
  for (int j = 0; j < 4; ++j) av[j] = a[c0 + tc*4 + j];
#pragma unroll
  for (int i = 0; i < 4; ++i) {
    int r = r0 + tr*4 + i;
    int c = c0 + tc*4;
    unsigned short hb[4], qb[4];
#pragma unroll
    for (int j = 0; j < 4; ++j) {
      float h = acc[i][j];
      hb[j] = f2bf(h);
      qb[j] = f2bf(h * av[j]);
      hT[(size_t)(c + j) * N_ + r] = hb[j];
    }
    *(uint2*)&hK[(size_t)r * OUTF_ + c] = *(uint2*)hb;
    *(uint2*)&hQ[(size_t)r * OUTF_ + c] = *(uint2*)qb;
  }
}

// ---------------------------------------------------------------------------
// Kernel 2: fused masked flash attention.  Q=h*a, K=V=h.  scale = 1/8.
// 4 waves x 16 q-rows. KV tile = 64. Online softmax in log2 domain.
// ---------------------------------------------------------------------------
__global__ __launch_bounds__(256, 2) void k_attn(
    const unsigned short* __restrict__ hQ, const unsigned short* __restrict__ hK,
    const unsigned short* __restrict__ hT, const int* __restrict__ adj,
    float* __restrict__ Opart, float* __restrict__ ml)
{
  // LDS: Krow 32KB (swizzled), KT 32KB (swizzled), P 4*16*144B
  __shared__ __align__(16) unsigned char smem[32768 + 32768 + 4*16*144];
  unsigned char* Krow = smem;
  unsigned char* KTl  = smem + 32768;

  int tid = threadIdx.x;
  int w = tid >> 6, l = tid & 63, g = l >> 4, li = l & 15;
  unsigned char* Pl = smem + 65536 + w * 2304;

  int qr0 = blockIdx.x * 64 + w * 16;
  int split = blockIdx.y;
  int t0 = split * TILES_PER_SPLIT;

  bf16x8 Qf[8];
  {
    const unsigned short* qp = hQ + (size_t)(qr0 + li) * OUTF_ + g * 8;
#pragma unroll
    for (int kt = 0; kt < 8; ++kt)
      Qf[kt] = *(const bf16x8*)(qp + kt * 32);
  }
  f32x4 O[16];
  const f32x4 zero4 = {0.f, 0.f, 0.f, 0.f};
#pragma unroll
  for (int i = 0; i < 16; ++i) O[i] = zero4;
  float m_r[4], l_r[4];
#pragma unroll
  for (int s = 0; s < 4; ++s) { m_r[s] = -1e30f; l_r[s] = 0.f; }

  const float SCALE = 0.18033688011112042f; // log2(e)/8

#pragma unroll 1
  for (int t = 0; t < TILES_PER_SPLIT; ++t) {
    int j0 = (t0 + t) * BK;
    // ---- stage K row-major [64][256] bf16, XOR-swizzled via pre-swizzled src
#pragma unroll
    for (int p = 0; p < 8; ++p) {
      int ch = tid + p * 256;            // 0..2047 chunks of 16B
      int row = ch >> 5;
      int c16 = ch & 31;
      const unsigned short* src = hK + (size_t)(j0 + row) * OUTF_ + ((c16 ^ (row & 7)) * 8);
      __builtin_amdgcn_global_load_lds(
          (const __attribute__((address_space(1))) void*)src,
          (__attribute__((address_space(3))) void*)(Krow + (p * 256 + w * 64) * 16),
          16, 0, 0);
    }
    // ---- stage V^T [256][64] bf16 from hT, XOR-swizzled
#pragma unroll
    for (int p = 0; p < 8; ++p) {
      int ch = tid + p * 256;
      int d = ch >> 3;
      int c = ch & 7;
      const unsigned short* src = hT + (size_t)d * N_ + j0 + ((c ^ (d & 7)) * 8);
      __builtin_amdgcn_global_load_lds(
          (const __attribute__((address_space(1))) void*)src,
          (__attribute__((address_space(3))) void*)(KTl + (p * 256 + w * 64) * 16),
          16, 0, 0);
    }
    // ---- adjacency mask for this tile (16 dwords per lane)
    int adjv[4][4];
#pragma unroll
    for (int s = 0; s < 4; ++s)
#pragma unroll
      for (int jt = 0; jt < 4; ++jt)
        adjv[s][jt] = adj[(size_t)(qr0 + 4*g + s) * N_ + j0 + jt*16 + li];
    __syncthreads();   // drains vmcnt (gload_lds + adj) then barrier

    // ---- S = Q K^T   (S[jt]: rows 4g+s, cols jt*16+li)
    f32x4 S[4];
#pragma unroll
    for (int jt = 0; jt < 4; ++jt) S[jt] = zero4;
#pragma unroll
    for (int jt = 0; jt < 4; ++jt) {
      unsigned roff = (unsigned)(jt * 16 + li) * 512;
#pragma unroll
      for (int kt = 0; kt < 8; ++kt) {
        bf16x8 kf = *(const bf16x8*)(Krow + roff + (((kt*4 + g) ^ (li & 7)) * 16));
        S[jt] = __builtin_amdgcn_mfma_f32_16x16x32_bf16(Qf[kt], kf, S[jt], 0, 0, 0);
      }
    }
    // ---- masked online softmax (log2 domain)
    float alpha[4];
    float pv[4][4];
    bool need = false;
#pragma unroll
    for (int s = 0; s < 4; ++s) {
      float vals[4], mx = -3e38f;
#pragma unroll
      for (int jt = 0; jt < 4; ++jt) {
        float sv = S[jt][s] * SCALE;
        sv = (adjv[s][jt] != 0) ? sv : -3e38f;
        vals[jt] = sv;
        mx = fmaxf(mx, sv);
      }
#pragma unroll
      for (int off = 1; off < 16; off <<= 1)
        mx = fmaxf(mx, __shfl_xor(mx, off));
      float mn = fmaxf(m_r[s], mx);
      float al = exp2f(m_r[s] - mn);
      alpha[s] = al;
      need |= (al != 1.f);
      float ssum = 0.f;
#pragma unroll
      for (int jt = 0; jt < 4; ++jt) {
        float p = exp2f(vals[jt] - mn);
        pv[s][jt] = p;
        ssum += p;
      }
#pragma unroll
      for (int off = 1; off < 16; off <<= 1)
        ssum += __shfl_xor(ssum, off);
      l_r[s] = l_r[s] * al + ssum;
      m_r[s] = mn;
    }
    if (__any(need)) {
#pragma unroll
      for (int dt = 0; dt < 16; ++dt)
#pragma unroll
        for (int s = 0; s < 4; ++s)
          O[dt][s] *= alpha[s];
    }
    // ---- P -> LDS (wave-private, [16][72] bf16)
#pragma unroll
    for (int s = 0; s < 4; ++s) {
      unsigned rb = (unsigned)(4*g + s) * 144;
#pragma unroll
      for (int jt = 0; jt < 4; ++jt)
        *(unsigned short*)(Pl + rb + (jt*16 + li) * 2) = f2bf(pv[s][jt]);
    }
    asm volatile("s_waitcnt lgkmcnt(0)" ::: "memory");
    // ---- O += P V
#pragma unroll
    for (int kt2 = 0; kt2 < 2; ++kt2) {
      bf16x8 pf = *(const bf16x8*)(Pl + (unsigned)li * 144 + kt2 * 64 + g * 16);
#pragma unroll
      for (int dt = 0; dt < 16; ++dt) {
        unsigned d = (unsigned)(dt * 16 + li);
        bf16x8 vf = *(const bf16x8*)(KTl + d * 128 + (((kt2*4 + g) ^ (li & 7)) * 16));
        O[dt] = __builtin_amdgcn_mfma_f32_16x16x32_bf16(pf, vf, O[dt], 0, 0, 0);
      }
    }
    __syncthreads();   // all waves done reading before next stage
  }
  // ---- epilogue: partial O, m, l
  size_t obase = ((size_t)split * N_ + qr0) * OUTF_;
#pragma unroll
  for (int dt = 0; dt < 16; ++dt)
#pragma unroll
    for (int s = 0; s < 4; ++s)
      Opart[obase + (size_t)(4*g + s) * OUTF_ + dt*16 + li] = O[dt][s];
  if (li == 0) {
#pragma unroll
    for (int s = 0; s < 4; ++s) {
      int row = qr0 + 4*g + s;
      ml[((size_t)split*2 + 0) * N_ + row] = m_r[s];
      ml[((size_t)split*2 + 1) * N_ + row] = l_r[s];
    }
  }
}

// ---------------------------------------------------------------------------
// Kernel 3: combine KV-splits, normalize, ELU.
// ---------------------------------------------------------------------------
__global__ __launch_bounds__(256) void k_combine(
    const float* __restrict__ Opart, const float* __restrict__ ml,
    float* __restrict__ out)
{
  int idx = blockIdx.x * 256 + threadIdx.x;   // N * 64 threads
  int row = idx >> 6;
  int c = (idx & 63) * 4;
  float ms[KVSPLIT], ls[KVSPLIT];
  float M = -3e38f;
#pragma unroll
  for (int s = 0; s < KVSPLIT; ++s) {
    ms[s] = ml[((size_t)s*2 + 0) * N_ + row];
    ls[s] = ml[((size_t)s*2 + 1) * N_ + row];
    M = fmaxf(M, ms[s]);
  }
  float L = 0.f;
  float a0 = 0.f, a1 = 0.f, a2 = 0.f, a3 = 0.f;
#pragma unroll
  for (int s = 0; s < KVSPLIT; ++s) {
    float wgt = exp2f(ms[s] - M);
    L += ls[s] * wgt;
    float4 o = *(const float4*)(Opart + ((size_t)s * N_ + row) * OUTF_ + c);
    a0 += o.x * wgt; a1 += o.y * wgt; a2 += o.z * wgt; a3 += o.w * wgt;
  }
  float inv = 1.f / L;
  float r0 = a0 * inv, r1 = a1 * inv, r2 = a2 * inv, r3 = a3 * inv;
  float4 r;
  r.x = r0 > 0.f ? r0 : expm1f(r0);
  r.y = r1 > 0.f ? r1 : expm1f(r1);
  r.z = r2 > 0.f ? r2 : expm1f(r2);
  r.w = r3 > 0.f ? r3 : expm1f(r3);
  *(float4*)(out + (size_t)row * OUTF_ + c) = r;
}

// ---------------------------------------------------------------------------
extern "C" void kernel_launch(void* const* d_in, const int* in_sizes, int n_in,
                              void* d_out, int out_size, void* d_ws, size_t ws_size,
                              hipStream_t stream) {
  const float* x  = (const float*)d_in[0];
  const int* adj  = (const int*)d_in[1];
  const float* W  = (const float*)d_in[2];
  const float* a  = (const float*)d_in[3];
  float* out = (float*)d_out;
  char* ws = (char*)d_ws;

  unsigned short* hK = (unsigned short*)(ws);                             // 4 MB
  unsigned short* hQ = (unsigned short*)(ws + (size_t)4*1024*1024);       // 4 MB
  unsigned short* hT = (unsigned short*)(ws + (size_t)8*1024*1024);       // 4 MB
  float* Opart = (float*)(ws + (size_t)12*1024*1024);                     // 32 MB
  float* ml    = (float*)(ws + (size_t)12*1024*1024
                             + (size_t)KVSPLIT*N_*OUTF_*4);               // 256 KB

  dim3 g1(N_/64, OUTF_/64);
  k_gemm_h<<<g1, 256, 0, stream>>>(x, W, a, hK, hQ, hT);
  dim3 g2(N_/64, KVSPLIT);
  k_attn<<<g2, 256, 0, stream>>>(hQ, hK, hT, adj, Opart, ml);
  k_combine<<<(N_*64)/256, 256, 0, stream>>>(Opart, ml, out);
}